// Round 10
// baseline (244.661 us; speedup 1.0000x reference)
//
#include <hip/hip_runtime.h>
#include <stdint.h>

#define C_CH   1024
#define T_DIM  16384
#define NSTEPS (T_DIM - 16)   // 16368
#define PAD    8
#define TP     (T_DIM + 16)   // padded time length 16400
#define SEG    64             // time steps per lane

// ws layout:
//   [0, 8*T_DIM*sizeof(double))  : double partial[8][T_DIM]   (1 MiB)
//   [1 MiB, +TP*4)               : float  colmean[TP]
#define WS_CM_OFFSET (8u * T_DIM * sizeof(double))

// ---------------- Kernel 1: per-row-chunk column partial sums ----------------
__global__ __launch_bounds__(128) void colsum_partial(const float* __restrict__ inp,
                                                      double* __restrict__ part) {
    int col4 = (blockIdx.x * 128 + threadIdx.x) * 4;  // 0..16380 step 4
    int rc   = blockIdx.y;                            // 0..7 (row chunk of 128)
    const float* p = inp + (size_t)rc * 128 * T_DIM + col4;
    double ax = 0.0, ay = 0.0, az = 0.0, aw = 0.0;
    #pragma unroll 16
    for (int r = 0; r < 128; ++r) {
        float4 v = *(const float4*)(p + (size_t)r * T_DIM);
        ax += (double)v.x; ay += (double)v.y; az += (double)v.z; aw += (double)v.w;
    }
    double* q = part + (size_t)rc * T_DIM + col4;
    q[0] = ax; q[1] = ay; q[2] = az; q[3] = aw;
}

// ---------------- Kernel 2: reduce partials -> padded column means, + tail copy ----------------
__global__ void colmean_tail(const double* __restrict__ part, const float* __restrict__ inp,
                             float* __restrict__ cm, float* __restrict__ out) {
    int i = blockIdx.x * 256 + threadIdx.x;   // 0..16639
    if (i < TP) {
        float v = 0.0f;
        if (i >= PAD && i < T_DIM + PAD) {
            int col = i - PAD;
            double t = 0.0;
            #pragma unroll
            for (int r = 0; r < 8; ++r) t += part[(size_t)r * T_DIM + col];
            v = (float)(t * (1.0 / 1024.0));        // /1024 is exact
        }
        cm[i] = v;
    }
    if (i < C_CH * 16) {                       // tail columns NSTEPS..T_DIM-1
        int c = i >> 4, j = i & 15;
        size_t idx = (size_t)c * T_DIM + NSTEPS + j;
        out[idx] = inp[idx];
    }
}

// ---------------- Kernel 3: cache-resident row-parallel scan ----------------
// Block (256 thr) = one channel; lane l owns [64l, 64l+64). 4096 waves total
// -> 4 blocks/CU -> 16 waves/CU = 4 waves/SIMD: dep-chain + load-latency
// stalls of one wave are covered by the other three (the 56-us version had
// 0.5 waves/SIMD). No LDS row staging: block working set = 64 KB row +
// 64 KB cm, re-read ~5x from L1/L2/L3 (input is L3-resident after colsum;
// FETCH=33MB<67MB proved that). Spikes -> 2 bitmask regs -> LDS transpose
// -> coalesced stores.
__global__ __launch_bounds__(256, 4) void scan_kernel(const float* __restrict__ inp,
                                                      const float* __restrict__ cm,
                                                      float* __restrict__ out) {
    __shared__ uint32_t bm[256][2];   // 2 KB spike bitmasks

    const int ch = blockIdx.x;
    const int l  = threadIdx.x;                 // 0..255
    const float* row  = inp + (size_t)ch * T_DIM;
    float*       orow = out + (size_t)ch * T_DIM;

    const int t0  = l << 6;                     // own segment start
    const int nwu = min(16, t0 >> 4);           // warmup iters: 0,4,8,12 then 16
    const int tw  = t0 - (nwu << 4);            // warmup start (>= 0; exact state at 0)

    // ---- init window: xs = inp_padded[ch, tw..tw+16), ms = cm[tw..tw+16) ----
    float xs[16], ms[16];
    {
        const float4* cp = (const float4*)(cm + tw);
        float4 m0 = cp[0], m1 = cp[1], m2 = cp[2], m3 = cp[3];
        float mt[16] = {m0.x,m0.y,m0.z,m0.w, m1.x,m1.y,m1.z,m1.w,
                        m2.x,m2.y,m2.z,m2.w, m3.x,m3.y,m3.z,m3.w};
        #pragma unroll
        for (int j = 0; j < 16; ++j) ms[j] = mt[j];

        if (tw == 0) {                          // padded [0,16) = 8 zeros + raw [0,8)
            float4 x2 = *(const float4*)(row);
            float4 x3 = *(const float4*)(row + 4);
            float xt[8] = {x2.x,x2.y,x2.z,x2.w, x3.x,x3.y,x3.z,x3.w};
            #pragma unroll
            for (int j = 0; j < 8; ++j) { xs[j] = 0.0f; xs[j + 8] = xt[j]; }
        } else {                                // raw [tw-8, tw+8), 16B-aligned
            const float* rp = row + tw - 8;
            float4 x0 = *(const float4*)(rp),     x1 = *(const float4*)(rp + 4),
                   x2 = *(const float4*)(rp + 8), x3 = *(const float4*)(rp + 12);
            float xt[16] = {x0.x,x0.y,x0.z,x0.w, x1.x,x1.y,x1.z,x1.w,
                            x2.x,x2.y,x2.z,x2.w, x3.x,x3.y,x3.z,x3.w};
            #pragma unroll
            for (int j = 0; j < 16; ++j) xs[j] = xt[j];
        }
    }
    float win = 0.0f;
    #pragma unroll
    for (int j = 0; j < 16; ++j) win = fmaf(xs[j], ms[j], win);

    float w = 1.0f, mem = 0.0f, spf = 0.0f;     // exact when tw==0; converged otherwise

    // ---- warmup: nwu iterations (max 16), no spike recording ----
    for (int it = 0; it < nwu; ++it) {
        const int t = tw + (it << 4);
        const float* rp = row + t + 8;          // raw [t+8, t+24), in-bounds (t<=16304)
        float4 a0 = *(const float4*)(rp),      a1 = *(const float4*)(rp + 4),
               a2 = *(const float4*)(rp + 8),  a3 = *(const float4*)(rp + 12);
        const float4* cp = (const float4*)(cm + t + 16);
        float4 b0 = cp[0], b1 = cp[1], b2 = cp[2], b3 = cp[3];
        float xn[16] = {a0.x,a0.y,a0.z,a0.w, a1.x,a1.y,a1.z,a1.w,
                        a2.x,a2.y,a2.z,a2.w, a3.x,a3.y,a3.z,a3.w};
        float mn[16] = {b0.x,b0.y,b0.z,b0.w, b1.x,b1.y,b1.z,b1.w,
                        b2.x,b2.y,b2.z,b2.w, b3.x,b3.y,b3.z,b3.w};
        #pragma unroll
        for (int j = 0; j < 16; ++j) {
            w = fminf(fmaxf(fmaf(0.5f, w, 0.5f * win), -1.0f), 3.0f);
            float x = xs[j];
            mem = fmaf(0.95f, mem, fmaf(w, x, -spf));   // spf = prev spike = reset
            spf = (mem > 1.0f) ? 1.0f : 0.0f;
            win = fmaf(xn[j], mn[j], fmaf(-x, ms[j], win));
            xs[j] = xn[j]; ms[j] = mn[j];
        }
    }

    // ---- main: 4 unrolled iterations; spikes -> bitmask regs ----
    uint32_t sb0 = 0, sb1 = 0;
    #pragma unroll
    for (int q = 0; q < 4; ++q) {
        const int t = t0 + (q << 4);
        const float* rp = row + t + 8;
        float4 a0 = *(const float4*)(rp), a1 = *(const float4*)(rp + 4);
        float4 a2, a3;
        if (q == 3) {                            // only lane 255 can cross row end
            const int p2 = t + 16, p3 = t + 20;
            a2 = *(const float4*)(row + min(p2, T_DIM - 4));
            a3 = *(const float4*)(row + min(p3, T_DIM - 4));
            if (p2 >= T_DIM) a2 = make_float4(0.f, 0.f, 0.f, 0.f);   // right zero-pad
            if (p3 >= T_DIM) a3 = make_float4(0.f, 0.f, 0.f, 0.f);
        } else {
            a2 = *(const float4*)(rp + 8); a3 = *(const float4*)(rp + 12);
        }
        const float4* cp = (const float4*)(cm + t + 16);   // <= 16399, in-bounds
        float4 b0 = cp[0], b1 = cp[1], b2 = cp[2], b3 = cp[3];
        float xn[16] = {a0.x,a0.y,a0.z,a0.w, a1.x,a1.y,a1.z,a1.w,
                        a2.x,a2.y,a2.z,a2.w, a3.x,a3.y,a3.z,a3.w};
        float mn[16] = {b0.x,b0.y,b0.z,b0.w, b1.x,b1.y,b1.z,b1.w,
                        b2.x,b2.y,b2.z,b2.w, b3.x,b3.y,b3.z,b3.w};
        uint32_t m16 = 0;
        #pragma unroll
        for (int j = 0; j < 16; ++j) {
            w = fminf(fmaxf(fmaf(0.5f, w, 0.5f * win), -1.0f), 3.0f);
            float x = xs[j];
            mem = fmaf(0.95f, mem, fmaf(w, x, -spf));   // spf = prev spike = reset
            bool sp = (mem > 1.0f);
            spf = sp ? 1.0f : 0.0f;
            m16 |= sp ? (1u << j) : 0u;
            win = fmaf(xn[j], mn[j], fmaf(-x, ms[j], win));
            xs[j] = xn[j]; ms[j] = mn[j];
        }
        if (q < 2) sb0 |= m16 << (q * 16);       // static packing (q unrolled)
        else       sb1 |= m16 << ((q - 2) * 16);
    }

    // ---- write: bitmask transpose via LDS -> coalesced 4 KB stores ----
    bm[l][0] = sb0; bm[l][1] = sb1;
    __syncthreads();
    #pragma unroll
    for (int k = 0; k < 16; ++k) {
        const int p = k * 1024 + (l << 2);               // output position
        uint32_t word = bm[p >> 6][(p >> 5) & 1];
        uint32_t bits = (word >> (p & 31)) & 0xFu;
        if (k < 15 || l < 252) {   // p >= NSTEPS handled by colmean_tail copy
            *(float4*)(orow + p) = make_float4((bits & 1u) ? 1.f : 0.f,
                                               (bits & 2u) ? 1.f : 0.f,
                                               (bits & 4u) ? 1.f : 0.f,
                                               (bits & 8u) ? 1.f : 0.f);
        }
    }
}

extern "C" void kernel_launch(void* const* d_in, const int* in_sizes, int n_in,
                              void* d_out, int out_size, void* d_ws, size_t ws_size,
                              hipStream_t stream) {
    const float* inp = (const float*)d_in[0];
    float* out = (float*)d_out;
    double* part = (double*)d_ws;
    float* cm = (float*)((char*)d_ws + WS_CM_OFFSET);

    colsum_partial<<<dim3(32, 8), 128, 0, stream>>>(inp, part);
    colmean_tail<<<dim3(65), 256, 0, stream>>>(part, inp, cm, out);
    scan_kernel<<<dim3(C_CH), 256, 0, stream>>>(inp, cm, out);
}

// Round 11
// 172.584 us; speedup vs baseline: 1.4176x; 1.4176x over previous
//
#include <hip/hip_runtime.h>
#include <stdint.h>

#define C_CH   1024
#define T_DIM  16384
#define NSTEPS (T_DIM - 16)   // 16368
#define TP     (T_DIM + 16)   // padded time length 16400

// Workspace: only cm lives in ws. The 8 MB f64 partial array is staged in the
// OUTPUT buffer (out is fully rewritten by scan afterwards; tail copy moved
// into scan so colmean never writes out while partials are live).

// ---------------- Kernel 1: row-wise column partial sums ----------------
// grid (4 col-quarters, 64 row-groups) x 256 thr. Block (q,g): rows
// [16g,16g+16), cols [4096q, 4096q+4096). Each row chunk is a 16 KB
// SEQUENTIAL stream (vs 1-4 KB column-strided in all prior variants).
// f64 VGPR accumulators -> exact; partials part[64][16384] f64.
__global__ __launch_bounds__(256) void colsum_partial(const float* __restrict__ inp,
                                                      double* __restrict__ part) {
    const int q = blockIdx.x, g = blockIdx.y, t = threadIdx.x;
    const int c0 = q * 4096;
    const float* p = inp + (size_t)(g * 16) * T_DIM + c0;
    double acc[4][4];
    #pragma unroll
    for (int i = 0; i < 4; ++i)
        #pragma unroll
        for (int j = 0; j < 4; ++j) acc[i][j] = 0.0;
    #pragma unroll 4
    for (int r = 0; r < 16; ++r) {
        const float* pr = p + (size_t)r * T_DIM;
        #pragma unroll
        for (int i = 0; i < 4; ++i) {
            float4 v = *(const float4*)(pr + (i * 256 + t) * 4);
            acc[i][0] += v.x; acc[i][1] += v.y; acc[i][2] += v.z; acc[i][3] += v.w;
        }
    }
    double* qp = part + (size_t)g * T_DIM + c0;
    #pragma unroll
    for (int i = 0; i < 4; ++i) {
        double2 lo = {acc[i][0], acc[i][1]}, hi = {acc[i][2], acc[i][3]};
        *(double2*)(qp + (i * 256 + t) * 4)     = lo;
        *(double2*)(qp + (i * 256 + t) * 4 + 2) = hi;
    }
}

// ---------------- Kernel 2: reduce 64 partials -> padded column means ----------------
__global__ void colmean_k(const double* __restrict__ part, float* __restrict__ cm) {
    int i = blockIdx.x * 256 + threadIdx.x;   // 0..16639
    if (i >= TP) return;
    float v = 0.0f;
    if (i >= 8 && i < T_DIM + 8) {
        int col = i - 8;
        double s = 0.0;
        #pragma unroll 8
        for (int r = 0; r < 64; ++r) s += part[(size_t)r * T_DIM + col];
        v = (float)(s * (1.0 / 1024.0));      // /1024 exact
    }
    cm[i] = v;
}

// ---------------- scan helpers ----------------
// 256B-segment XOR swizzle: segment seg = b>>8, 16B chunk c = (b>>4)&15;
// physical chunk = c ^ (seg&7). A wave's lanes (seg == thread id, consecutive)
// spread uniformly over all 8 bank-quads -> conflict-free ds_read_b128.
__device__ __forceinline__ float4 swz_ld(const float* base, int b) {
    int a = (b & ~255) | ((((b >> 4) & 15) ^ ((b >> 8) & 7)) << 4);
    return *(const float4*)((const char*)base + a);
}

// ---------------- Kernel 3: row-parallel scan, 4 waves/block ----------------
// Block (256 thr) = one channel; thread t owns steps [64t, 64t+64).
// Round-7's memory pattern (entire 64 KB row staged ONCE as a sequential
// global_load_lds stream, FETCH=33MB proved L3-friendly) + round-10's TLP
// (2 blocks/CU x 4 waves = 8 waves/CU, 4x round-7). Warmup 256 steps reads
// preceding threads' segments from the same LDS row -> no extra HBM fetch.
// Swizzle on the GLOBAL source (G21/m173), matching XOR on reads.
__global__ __launch_bounds__(256) void scan_kernel(const float* __restrict__ inp,
                                                   const float* __restrict__ cm,
                                                   float* __restrict__ out) {
    __shared__ float    rowl[T_DIM + 8];   // 64 KB swizzled row + 32 B zero pad
    __shared__ uint32_t bm[256][2];        // 2 KB spike bitmasks

    const int ch   = blockIdx.x;
    const int t    = threadIdx.x;          // 0..255
    const int wv   = t >> 6, lane = t & 63;
    const float* row  = inp + (size_t)ch * T_DIM;
    float*       orow = out + (size_t)ch * T_DIM;

    // ---- stage: wave wv stages regions R = i*4+wv (1 KB each), linear LDS ----
    #pragma unroll
    for (int i = 0; i < 16; ++i) {
        const int R   = i * 4 + wv;                    // 1 KB region, wave-uniform
        const int seg = R * 4 + (lane >> 4);           // 256 B segment
        const float* src = row + seg * 64 + (((lane & 15) ^ (seg & 7)) << 2);
        __builtin_amdgcn_global_load_lds(
            (const __attribute__((address_space(1))) void*)src,
            (__attribute__((address_space(3))) void*)(rowl + R * 256),
            16, 0, 0);
    }
    if (t < 2) *(float4*)(rowl + T_DIM + t * 4) = make_float4(0.f, 0.f, 0.f, 0.f);
    asm volatile("s_waitcnt vmcnt(0)" ::: "memory");
    __syncthreads();                                   // cross-wave region deps

    // ---- init window at tw (warmup start; exact state when tw==0) ----
    const int t0  = t << 6;
    const int nwu = min(16, t0 >> 4);                  // 0,4,8,12 then 16
    const int tw  = t0 - (nwu << 4);                   // >= 0

    float xs[16], ms[16];
    {
        const float4* cp = (const float4*)(cm + tw);
        float4 m0 = cp[0], m1 = cp[1], m2 = cp[2], m3 = cp[3];
        float mt[16] = {m0.x,m0.y,m0.z,m0.w, m1.x,m1.y,m1.z,m1.w,
                        m2.x,m2.y,m2.z,m2.w, m3.x,m3.y,m3.z,m3.w};
        #pragma unroll
        for (int j = 0; j < 16; ++j) ms[j] = mt[j];

        if (tw == 0) {                                 // padded [0,16) = 8 zeros + raw [0,8)
            float4 x2 = swz_ld(rowl, 0), x3 = swz_ld(rowl, 16);
            float xt[8] = {x2.x,x2.y,x2.z,x2.w, x3.x,x3.y,x3.z,x3.w};
            #pragma unroll
            for (int j = 0; j < 8; ++j) { xs[j] = 0.0f; xs[j + 8] = xt[j]; }
        } else {                                       // raw [tw-8, tw+8)
            const int b = tw * 4 - 32;
            float4 x0 = swz_ld(rowl, b),      x1 = swz_ld(rowl, b + 16),
                   x2 = swz_ld(rowl, b + 32), x3 = swz_ld(rowl, b + 48);
            float xt[16] = {x0.x,x0.y,x0.z,x0.w, x1.x,x1.y,x1.z,x1.w,
                            x2.x,x2.y,x2.z,x2.w, x3.x,x3.y,x3.z,x3.w};
            #pragma unroll
            for (int j = 0; j < 16; ++j) xs[j] = xt[j];
        }
    }
    float win = 0.0f;
    #pragma unroll
    for (int j = 0; j < 16; ++j) win = fmaf(xs[j], ms[j], win);

    float w = 1.0f, mem = 0.0f, spf = 0.0f;            // exact when tw==0

    // ---- warmup: up to 16 iterations (guarded; only threads 0..3 skip some) ----
    #pragma unroll
    for (int it = 0; it < 16; ++it) {
        if (it < nwu) {
            const int tt = tw + (it << 4);
            const int b  = tt * 4 + 32;                // raw [tt+8, tt+24)
            float4 a0 = swz_ld(rowl, b),      a1 = swz_ld(rowl, b + 16),
                   a2 = swz_ld(rowl, b + 32), a3 = swz_ld(rowl, b + 48);
            const float4* cp = (const float4*)(cm + tt + 16);
            float4 b0 = cp[0], b1 = cp[1], b2 = cp[2], b3 = cp[3];
            float xn[16] = {a0.x,a0.y,a0.z,a0.w, a1.x,a1.y,a1.z,a1.w,
                            a2.x,a2.y,a2.z,a2.w, a3.x,a3.y,a3.z,a3.w};
            float mn[16] = {b0.x,b0.y,b0.z,b0.w, b1.x,b1.y,b1.z,b1.w,
                            b2.x,b2.y,b2.z,b2.w, b3.x,b3.y,b3.z,b3.w};
            #pragma unroll
            for (int j = 0; j < 16; ++j) {
                w = fminf(fmaxf(fmaf(0.5f, w, 0.5f * win), -1.0f), 3.0f);
                float x = xs[j];
                mem = fmaf(0.95f, mem, fmaf(w, x, -spf));   // spf = prev spike
                spf = (mem > 1.0f) ? 1.0f : 0.0f;
                win = fmaf(xn[j], mn[j], fmaf(-x, ms[j], win));
                xs[j] = xn[j]; ms[j] = mn[j];
            }
        }
    }

    // ---- main: 4 iterations (64 own steps); spikes -> bitmask regs ----
    uint32_t sb0 = 0, sb1 = 0;
    #pragma unroll
    for (int q = 0; q < 4; ++q) {
        const int tt = t0 + (q << 4);
        const int b  = tt * 4 + 32;                    // t=255,q=3 reads into pad: ok
        float4 a0 = swz_ld(rowl, b),      a1 = swz_ld(rowl, b + 16),
               a2 = swz_ld(rowl, b + 32), a3 = swz_ld(rowl, b + 48);
        const float4* cp = (const float4*)(cm + tt + 16);   // max idx 16399 < TP
        float4 b0 = cp[0], b1 = cp[1], b2 = cp[2], b3 = cp[3];
        float xn[16] = {a0.x,a0.y,a0.z,a0.w, a1.x,a1.y,a1.z,a1.w,
                        a2.x,a2.y,a2.z,a2.w, a3.x,a3.y,a3.z,a3.w};
        float mn[16] = {b0.x,b0.y,b0.z,b0.w, b1.x,b1.y,b1.z,b1.w,
                        b2.x,b2.y,b2.z,b2.w, b3.x,b3.y,b3.z,b3.w};
        uint32_t m16 = 0;
        #pragma unroll
        for (int j = 0; j < 16; ++j) {
            w = fminf(fmaxf(fmaf(0.5f, w, 0.5f * win), -1.0f), 3.0f);
            float x = xs[j];
            mem = fmaf(0.95f, mem, fmaf(w, x, -spf));
            bool sp = (mem > 1.0f);
            spf = sp ? 1.0f : 0.0f;
            m16 |= sp ? (1u << j) : 0u;
            win = fmaf(xn[j], mn[j], fmaf(-x, ms[j], win));
            xs[j] = xn[j]; ms[j] = mn[j];
        }
        if (q < 2) sb0 |= m16 << (q * 16);
        else       sb1 |= m16 << ((q - 2) * 16);
    }

    // ---- write: bitmask transpose via LDS -> coalesced 4 KB stores ----
    bm[t][0] = sb0; bm[t][1] = sb1;
    __syncthreads();
    #pragma unroll
    for (int k = 0; k < 16; ++k) {
        const int p = k * 1024 + (t << 2);
        uint32_t word = bm[p >> 6][(p >> 5) & 1];
        uint32_t bits = (word >> (p & 31)) & 0xFu;
        if (k < 15 || t < 252) {                       // p >= NSTEPS handled below
            *(float4*)(orow + p) = make_float4((bits & 1u) ? 1.f : 0.f,
                                               (bits & 2u) ? 1.f : 0.f,
                                               (bits & 4u) ? 1.f : 0.f,
                                               (bits & 8u) ? 1.f : 0.f);
        }
    }
    if (t < 16) orow[NSTEPS + t] = row[NSTEPS + t];    // tail copy (moved from colmean)
}

extern "C" void kernel_launch(void* const* d_in, const int* in_sizes, int n_in,
                              void* d_out, int out_size, void* d_ws, size_t ws_size,
                              hipStream_t stream) {
    const float* inp = (const float*)d_in[0];
    float* out = (float*)d_out;
    double* part = (double*)d_out;          // 8 MB scratch inside out (rewritten by scan)
    float* cm = (float*)d_ws;               // 65.6 KB in workspace

    colsum_partial<<<dim3(4, 64), 256, 0, stream>>>(inp, part);
    colmean_k<<<dim3(65), 256, 0, stream>>>(part, cm);
    scan_kernel<<<dim3(C_CH), 256, 0, stream>>>(inp, cm, out);
}

// Round 13
// 159.507 us; speedup vs baseline: 1.5339x; 1.0820x over previous
//
#include <hip/hip_runtime.h>
#include <stdint.h>

#define C_CH   1024
#define T_DIM  16384
#define NSTEPS (T_DIM - 16)   // 16368
#define TP     (T_DIM + 16)   // 16400
#define SEG    256            // time steps per lane (scan)

// Layout: cm[TP] f32 at ws base. Partials f64[64][16384] (8 MB) live in OUT
// (rows 0..127) as scratch; scan fully rewrites out afterwards (stream-ordered).

// ---------------- Kernel 1: row-wise column partial sums ----------------
// grid (4 col-quarters, 64 row-groups) x 256 thr. Block: 16 rows x 16 KB
// SEQUENTIAL streams. f64 accumulators (exact). [verified: round 11]
__global__ __launch_bounds__(256) void colsum_partial(const float* __restrict__ inp,
                                                      double* __restrict__ part) {
    const int q = blockIdx.x, g = blockIdx.y, t = threadIdx.x;
    const int c0 = q * 4096;
    const float* p = inp + (size_t)(g * 16) * T_DIM + c0;
    double acc[4][4];
    #pragma unroll
    for (int i = 0; i < 4; ++i)
        #pragma unroll
        for (int j = 0; j < 4; ++j) acc[i][j] = 0.0;
    #pragma unroll 4
    for (int r = 0; r < 16; ++r) {
        const float* pr = p + (size_t)r * T_DIM;
        #pragma unroll
        for (int i = 0; i < 4; ++i) {
            float4 v = *(const float4*)(pr + (i * 256 + t) * 4);
            acc[i][0] += v.x; acc[i][1] += v.y; acc[i][2] += v.z; acc[i][3] += v.w;
        }
    }
    double* qp = part + (size_t)g * T_DIM + c0;
    #pragma unroll
    for (int i = 0; i < 4; ++i) {
        *(double2*)(qp + (i * 256 + t) * 4)     = make_double2(acc[i][0], acc[i][1]);
        *(double2*)(qp + (i * 256 + t) * 4 + 2) = make_double2(acc[i][2], acc[i][3]);
    }
}

// ---------------- Kernel 2: COALESCED partial reduce -> cm ----------------
// Block owns cols [256b, 256b+256): each iteration reads a 2 KB CONTIGUOUS
// slice of one partial row (round-11 version read 64 doubles at 128 KB
// stride per thread -> ~35 us; this is ~6 us).
__global__ __launch_bounds__(256) void colmean_coal(const double* __restrict__ part,
                                                    float* __restrict__ cm) {
    const int b = blockIdx.x, t = threadIdx.x;
    const int col = b * 256 + t;
    double s = 0.0;
    #pragma unroll 8
    for (int r = 0; r < 64; ++r) s += part[(size_t)r * T_DIM + col];
    cm[8 + col] = (float)(s * (1.0 / 1024.0));   // /1024 exact
    if (b == 0 && t < 8) cm[t] = 0.0f;           // left pad
    if (b == 1 && t < 8) cm[T_DIM + 8 + t] = 0.0f;   // right pad
}

// ---------------- scan helpers ----------------
// Swizzled LDS read: raw row byte offset b (16B-aligned) -> swizzled address.
// 1 KB segments; 16B chunk index XORed with (seg & 7). [verified: round 7]
__device__ __forceinline__ float4 swz_ld(const float* base, int b) {
    int a = (b & ~1023) | ((((b >> 4) & 63) ^ ((b >> 10) & 7)) << 4);
    return *(const float4*)((const char*)base + a);
}

// ---------------- Kernel 3: row-parallel per-channel scan ----------------
// One block (64 thr) = one channel; lane l owns [256l, 256l+256). Entire
// 64 KB row staged ONCE via 64 coalesced 1 KB global_load_lds (swizzle on
// the global source, G21/m173). Warmup region = preceding lane's segment,
// already in LDS. Single vmcnt(0); spikes -> bitmask -> LDS -> coalesced
// stores. [verified: rounds 7,8 @ 56.4 us] + tail copy folded in.
__global__ __launch_bounds__(64) void scan_kernel(const float* __restrict__ inp,
                                                  const float* __restrict__ cm,
                                                  float* __restrict__ out) {
    __shared__ float    rowl[T_DIM + 8];   // 64 KB swizzled row + 32 B zero pad
    __shared__ uint32_t bm[64][8];         // 2 KB spike bitmasks

    const int ch   = blockIdx.x;
    const int lane = threadIdx.x;
    const float* row  = inp + (size_t)ch * T_DIM;
    float*       orow = out + (size_t)ch * T_DIM;

    // ---- prologue: stage full row, swizzled source, linear LDS dest ----
    #pragma unroll
    for (int i = 0; i < 64; ++i) {
        const float* src = row + i * SEG + ((lane ^ (i & 7)) << 2);
        __builtin_amdgcn_global_load_lds(
            (const __attribute__((address_space(1))) void*)src,
            (__attribute__((address_space(3))) void*)(rowl + i * SEG),
            16, 0, 0);
    }
    if (lane < 2) {   // zero pad: raw [16384, 16392)
        *(float4*)(rowl + T_DIM + lane * 4) = make_float4(0.f, 0.f, 0.f, 0.f);
    }
    asm volatile("s_waitcnt vmcnt(0)" ::: "memory");
    __builtin_amdgcn_sched_barrier(0);

    // ---- init window at sW (warmup start; main start for lane 0) ----
    const int sW = (lane == 0) ? 0 : (lane - 1) * SEG;
    const int sM = lane * SEG;

    float xs[16], ms[16];
    {
        const float4* cp = (const float4*)(cm + sW);
        float4 m0 = cp[0], m1 = cp[1], m2 = cp[2], m3 = cp[3];
        float mt[16] = {m0.x,m0.y,m0.z,m0.w, m1.x,m1.y,m1.z,m1.w,
                        m2.x,m2.y,m2.z,m2.w, m3.x,m3.y,m3.z,m3.w};
        #pragma unroll
        for (int j = 0; j < 16; ++j) ms[j] = mt[j];

        if (sW == 0) {                        // lanes 0,1: 8 zeros + raw [0,8)
            float4 x2 = swz_ld(rowl, 0);
            float4 x3 = swz_ld(rowl, 16);
            float xt[8] = {x2.x,x2.y,x2.z,x2.w, x3.x,x3.y,x3.z,x3.w};
            #pragma unroll
            for (int j = 0; j < 8; ++j) { xs[j] = 0.0f; xs[j + 8] = xt[j]; }
        } else {                              // raw [sW-8, sW+8)
            const int b = sW * 4 - 32;
            float4 x0 = swz_ld(rowl, b),      x1 = swz_ld(rowl, b + 16),
                   x2 = swz_ld(rowl, b + 32), x3 = swz_ld(rowl, b + 48);
            float xt[16] = {x0.x,x0.y,x0.z,x0.w, x1.x,x1.y,x1.z,x1.w,
                            x2.x,x2.y,x2.z,x2.w, x3.x,x3.y,x3.z,x3.w};
            #pragma unroll
            for (int j = 0; j < 16; ++j) xs[j] = xt[j];
        }
    }
    float win = 0.0f;
    #pragma unroll
    for (int j = 0; j < 16; ++j) win = fmaf(xs[j], ms[j], win);

    float w = 1.0f, mem = 0.0f, spf = 0.0f;   // exact for lane 0; converged otherwise

    // ---- warmup: 16 iterations, lanes 1..63 only ----
    for (int it = 0; it < 16; ++it) {
        if (lane != 0) {
            const int b = sW * 4 + it * 64 + 32;          // raw [t+8, t+24)
            float4 a0 = swz_ld(rowl, b),      a1 = swz_ld(rowl, b + 16),
                   a2 = swz_ld(rowl, b + 32), a3 = swz_ld(rowl, b + 48);
            const float4* cp = (const float4*)(cm + sW + it * 16 + 16);
            float4 b0 = cp[0], b1 = cp[1], b2 = cp[2], b3 = cp[3];
            float xn[16] = {a0.x,a0.y,a0.z,a0.w, a1.x,a1.y,a1.z,a1.w,
                            a2.x,a2.y,a2.z,a2.w, a3.x,a3.y,a3.z,a3.w};
            float mn[16] = {b0.x,b0.y,b0.z,b0.w, b1.x,b1.y,b1.z,b1.w,
                            b2.x,b2.y,b2.z,b2.w, b3.x,b3.y,b3.z,b3.w};
            #pragma unroll
            for (int j = 0; j < 16; ++j) {
                w = fminf(fmaxf(fmaf(0.5f, w, 0.5f * win), -1.0f), 3.0f);
                float x = xs[j];
                mem = fmaf(0.95f, mem, fmaf(w, x, -spf));   // spf = prev spike
                spf = (mem > 1.0f) ? 1.0f : 0.0f;
                win = fmaf(xn[j], mn[j], fmaf(-x, ms[j], win));
                xs[j] = xn[j]; ms[j] = mn[j];
            }
        }
    }

    // ---- main: 16 unrolled iterations; spikes -> bitmask regs ----
    uint32_t sb[8] = {0, 0, 0, 0, 0, 0, 0, 0};
    #pragma unroll
    for (int q = 0; q < 16; ++q) {
        const int b = sM * 4 + q * 64 + 32;
        float4 a0 = swz_ld(rowl, b),      a1 = swz_ld(rowl, b + 16),
               a2 = swz_ld(rowl, b + 32), a3 = swz_ld(rowl, b + 48);
        const float4* cp = (const float4*)(cm + sM + q * 16 + 16);
        float4 b0 = cp[0], b1 = cp[1], b2 = cp[2], b3 = cp[3];
        float xn[16] = {a0.x,a0.y,a0.z,a0.w, a1.x,a1.y,a1.z,a1.w,
                        a2.x,a2.y,a2.z,a2.w, a3.x,a3.y,a3.z,a3.w};
        float mn[16] = {b0.x,b0.y,b0.z,b0.w, b1.x,b1.y,b1.z,b1.w,
                        b2.x,b2.y,b2.z,b2.w, b3.x,b3.y,b3.z,b3.w};
        uint32_t m16 = 0;
        #pragma unroll
        for (int j = 0; j < 16; ++j) {
            w = fminf(fmaxf(fmaf(0.5f, w, 0.5f * win), -1.0f), 3.0f);
            float x = xs[j];
            mem = fmaf(0.95f, mem, fmaf(w, x, -spf));       // spf = prev spike
            bool sp = (mem > 1.0f);
            spf = sp ? 1.0f : 0.0f;
            m16 |= sp ? (1u << j) : 0u;
            win = fmaf(xn[j], mn[j], fmaf(-x, ms[j], win));
            xs[j] = xn[j]; ms[j] = mn[j];
        }
        sb[q >> 1] |= m16 << ((q & 1) * 16);                // static index
    }

    // ---- write: bitmask transpose via LDS -> 64 coalesced 1 KB row stores ----
    *(uint4*)&bm[lane][0] = make_uint4(sb[0], sb[1], sb[2], sb[3]);
    *(uint4*)&bm[lane][4] = make_uint4(sb[4], sb[5], sb[6], sb[7]);
    #pragma unroll 8
    for (int seg = 0; seg < 64; ++seg) {
        uint32_t word = bm[seg][lane >> 3];
        uint32_t bits = (word >> ((lane & 7) * 4)) & 0xFu;
        float4 v = make_float4((bits & 1u) ? 1.f : 0.f, (bits & 2u) ? 1.f : 0.f,
                               (bits & 4u) ? 1.f : 0.f, (bits & 8u) ? 1.f : 0.f);
        if (seg < 63 || lane < 60)   // positions >= NSTEPS handled below
            *(float4*)(orow + seg * SEG + lane * 4) = v;
    }
    if (lane < 16) orow[NSTEPS + lane] = row[NSTEPS + lane];   // tail copy
}

extern "C" void kernel_launch(void* const* d_in, const int* in_sizes, int n_in,
                              void* d_out, int out_size, void* d_ws, size_t ws_size,
                              hipStream_t stream) {
    const float* inp = (const float*)d_in[0];
    float* out = (float*)d_out;
    double* part = (double*)d_out;          // 8 MB scratch in out (rewritten by scan)
    float* cm  = (float*)d_ws;              // 65.6 KB in workspace

    colsum_partial<<<dim3(4, 64), 256, 0, stream>>>(inp, part);
    colmean_coal<<<dim3(64), 256, 0, stream>>>(part, cm);
    scan_kernel<<<dim3(C_CH), 64, 0, stream>>>(inp, cm, out);
}